// Round 5
// baseline (1201.277 us; speedup 1.0000x reference)
//
#include <hip/hip_runtime.h>
#include <cmath>

// Problem constants (from reference)
#define N_INPUTS 2048
#define UNITS    2048
#define L_LAYERS 8
#define FANIN    4096
#define TOTAL    18432           // N_INPUTS + L*UNITS

// Decomposition
#define NTHREADS 256
#define RK       16              // rows (k) per block per layer
#define KC       (FANIN / RK)    // 256 partial rows
#define JTILE    1024            // columns per block (256 thr * 4)
#define NBLOCKS  (2 * KC)        // 512 blocks: (j-half, k-chunk) — 2/CU, co-resident

// Wave-parallel reduction of one partials column (KC=256 rows).
// All 64 lanes of the calling wave must participate. Returns sum in all lanes.
__device__ __forceinline__ float col_reduce(const float* __restrict__ P, int col)
{
    int lane = threadIdx.x & 63;
    float s = 0.f;
    #pragma unroll
    for (int m = 0; m < KC / 64; ++m)
        s += P[(size_t)(lane + m * 64) * UNITS + col];
    #pragma unroll
    for (int off = 32; off; off >>= 1)
        s += __shfl_down(s, off, 64);
    return __shfl(s, 0, 64);
}

// Software grid barrier (same construction as AMD's grid.sync()):
// release fence + device-scope arrive, acquire spin, acquire fence.
// cnt[i] is used exactly once per launch (zeroed by init_kernel).
__device__ __forceinline__ void grid_barrier(int* cnt)
{
    __syncthreads();
    if (threadIdx.x == 0) {
        __threadfence();   // release: drain stores, write back local L2
        __hip_atomic_fetch_add(cnt, 1, __ATOMIC_RELEASE, __HIP_MEMORY_SCOPE_AGENT);
        while (__hip_atomic_load(cnt, __ATOMIC_ACQUIRE, __HIP_MEMORY_SCOPE_AGENT) < NBLOCKS)
            __builtin_amdgcn_s_sleep(8);
        __threadfence();   // acquire: invalidate L1 / local L2
    }
    __syncthreads();
    asm volatile("" ::: "memory");   // no register-caching across the barrier
}

// ---------------------------------------------------------------------------
// init: zero the 8 barrier counters (d_ws is poisoned 0xAA before every call)
// ---------------------------------------------------------------------------
__global__ void init_kernel(int* __restrict__ cnt)
{
    if (threadIdx.x < L_LAYERS) cnt[threadIdx.x] = 0;
}

// ---------------------------------------------------------------------------
// Persistent fused kernel. Per layer i each block:
//   1. finalizes its 4 owned columns of state slot i from Pprev
//      (slot 0 = copy of x), making the slot visible for later layers;
//   2. computes its 16 gather activations:
//        idx <  i*2048  -> outputs[idx]   (materialized, >=1 barrier ago)
//        idx in slot i  -> recompute locally from Pprev
//        idx beyond     -> 0
//   3. MACs its prefetched 16x1024 weight tile into a float4 partial, stores
//      to Pcur;
//   4. prefetches layer i+1's weight tile into registers, THEN spins on the
//      grid barrier — the HBM weight stream stays in flight across the sync.
// ---------------------------------------------------------------------------
__global__ __launch_bounds__(NTHREADS, 2) void net_kernel(
    const float* __restrict__ x,
    const int*   __restrict__ node_inds,
    const float* __restrict__ Ws,
    const float* __restrict__ bs,
    float*       __restrict__ out,
    float*       __restrict__ outputs,
    float*       __restrict__ P0,
    float*       __restrict__ P1,
    int*         __restrict__ cnt)
{
    const int b    = blockIdx.x;
    const int t    = threadIdx.x;
    const int wv   = t >> 6;          // wave 0..3
    const int lane = t & 63;
    const int jhalf = b & 1;
    const int kc    = b >> 1;
    const int jbase = jhalf * JTILE + t * 4;
    const int col   = b * 4 + wv;     // this wave's owned state column

    __shared__ float gsh[RK];

    // prefetch layer-0 weight tile
    float4 w[RK];
    {
        const float4* W4 = (const float4*)(Ws + (size_t)kc * RK * UNITS + jbase);
        #pragma unroll
        for (int k = 0; k < RK; ++k)
            w[k] = W4[(size_t)k * (UNITS / 4)];
    }

    for (int i = 0; i < L_LAYERS; ++i) {
        const float* Pprev = (i & 1) ? P0 : P1;   // buffer written at layer i-1
        float*       Pcur  = (i & 1) ? P1 : P0;

        // ---- 1. finalize owned column of slot i
        if (i == 0) {
            if (lane == 0) outputs[col] = x[col];
        } else {
            float s = col_reduce(Pprev, col);
            float y = tanhf(s + bs[(i - 1) * UNITS + col]);
            if (lane == 0) outputs[(size_t)i * UNITS + col] = y;
        }

        // ---- 2. gather activations (4 wave-uniform indices per wave)
        #pragma unroll
        for (int j = 0; j < 4; ++j) {
            int q   = wv * 4 + j;
            int idx = node_inds[i * FANIN + kc * RK + q];
            float g;
            if (i == 0) {
                g = (idx < N_INPUTS) ? x[idx] : 0.f;
            } else if (idx < i * UNITS) {
                g = outputs[idx];
            } else if (idx < (i + 1) * UNITS) {
                int c = idx - i * UNITS;
                float s = col_reduce(Pprev, c);
                g = tanhf(s + bs[(i - 1) * UNITS + c]);
            } else {
                g = 0.f;
            }
            if (lane == 0) gsh[q] = g;
        }
        __syncthreads();

        // ---- 3. MAC with prefetched weights, store partial
        float4 a; a.x = 0.f; a.y = 0.f; a.z = 0.f; a.w = 0.f;
        #pragma unroll
        for (int k = 0; k < RK; ++k) {
            float g = gsh[k];
            a.x += g * w[k].x; a.y += g * w[k].y;
            a.z += g * w[k].z; a.w += g * w[k].w;
        }
        *(float4*)(Pcur + (size_t)kc * UNITS + jbase) = a;

        // ---- 4. prefetch next layer's tile, then barrier (loads in flight)
        if (i + 1 < L_LAYERS) {
            const float4* W4 = (const float4*)(
                Ws + ((size_t)(i + 1) * FANIN + (size_t)kc * RK) * UNITS + jbase);
            #pragma unroll
            for (int k = 0; k < RK; ++k)
                w[k] = W4[(size_t)k * (UNITS / 4)];
        }

        grid_barrier(&cnt[i]);
    }

    // ---- epilogue: layer 7 wrote P1 (i=7 odd -> Pcur=P1)
    {
        float s = col_reduce(P1, col);
        float y = tanhf(s + bs[(L_LAYERS - 1) * UNITS + col]);
        if (lane == 0) out[col] = y;
    }
}

// ---------------------------------------------------------------------------
extern "C" void kernel_launch(void* const* d_in, const int* in_sizes, int n_in,
                              void* d_out, int out_size, void* d_ws, size_t ws_size,
                              hipStream_t stream) {
    const float* x         = (const float*)d_in[0];
    const int*   node_inds = (const int*)  d_in[1];
    const float* Ws        = (const float*)d_in[2];
    const float* bs        = (const float*)d_in[3];
    float*       out       = (float*)d_out;
    float*       ws        = (float*)d_ws;

    float* outputs = ws;                        // TOTAL floats
    float* P0      = outputs + TOTAL;           // KC*UNITS floats (2 MiB)
    float* P1      = P0 + (size_t)KC * UNITS;   // KC*UNITS floats (2 MiB)
    int*   cnt     = (int*)(P1 + (size_t)KC * UNITS);  // L_LAYERS ints

    init_kernel<<<1, 64, 0, stream>>>(cnt);
    net_kernel<<<NBLOCKS, NTHREADS, 0, stream>>>(
        x, node_inds, Ws, bs, out, outputs, P0, P1, cnt);
}

// Round 6
// 855.141 us; speedup vs baseline: 1.4048x; 1.4048x over previous
//
#include <hip/hip_runtime.h>
#include <cmath>

// Problem constants (from reference)
#define N_INPUTS 2048
#define UNITS    2048
#define L_LAYERS 8
#define FANIN    4096
#define TOTAL    18432           // N_INPUTS + L*UNITS

// Decomposition
#define NTHREADS 256
#define RK       16              // rows (k) per block per layer
#define KC       (FANIN / RK)    // 256 partial rows
#define JTILE    1024            // columns per block (256 thr * 4)
#define NBLOCKS  (2 * KC)        // 512 blocks: (j-half, k-chunk) — 2/CU, co-resident

// Wave-parallel reduction of one partials column (KC=256 rows).
// All 64 lanes of the calling wave must participate. Returns sum in all lanes.
__device__ __forceinline__ float col_reduce(const float* __restrict__ P, int col)
{
    int lane = threadIdx.x & 63;
    float s = 0.f;
    #pragma unroll
    for (int m = 0; m < KC / 64; ++m)
        s += P[(size_t)(lane + m * 64) * UNITS + col];
    #pragma unroll
    for (int off = 32; off; off >>= 1)
        s += __shfl_down(s, off, 64);
    return __shfl(s, 0, 64);
}

// Software grid barrier. ONE release fence (wbl2) before arrive, RELAXED
// polling (no per-poll cache invalidate — the R5 killer), ONE acquire fence
// (inv) after exit. cnt is used exactly once per launch (zeroed by init).
__device__ __forceinline__ void grid_barrier(int* cnt)
{
    __syncthreads();
    if (threadIdx.x == 0) {
        __threadfence();   // release: push this block's stores past L2 (once)
        __hip_atomic_fetch_add(cnt, 1, __ATOMIC_RELAXED, __HIP_MEMORY_SCOPE_AGENT);
        while (__hip_atomic_load(cnt, __ATOMIC_RELAXED, __HIP_MEMORY_SCOPE_AGENT)
               < NBLOCKS)
            __builtin_amdgcn_s_sleep(16);
        __threadfence();   // acquire: drop stale L1/L2 lines (once)
    }
    __syncthreads();
    asm volatile("" ::: "memory");   // no register-caching across the barrier
}

// ---------------------------------------------------------------------------
// init: zero the 8 barrier counters with agent-scope atomic stores so the
// zeros land at the coherence point the barrier RMWs operate on (a plain
// store could sit dirty in one XCD's L2 against the 0xAA poison).
// ---------------------------------------------------------------------------
__global__ void init_kernel(int* __restrict__ cnt)
{
    if (threadIdx.x < L_LAYERS)
        __hip_atomic_store(&cnt[threadIdx.x], 0,
                           __ATOMIC_RELAXED, __HIP_MEMORY_SCOPE_AGENT);
}

// ---------------------------------------------------------------------------
// Persistent fused kernel. Per layer i each block:
//   1. finalizes its 4 owned columns of state slot i from Pprev
//      (slot 0 = copy of x);
//   2. computes its 16 gather activations:
//        idx <  i*2048  -> outputs[idx]   (materialized >=1 barrier ago)
//        idx in slot i  -> recompute locally from Pprev
//        idx beyond     -> 0               (never reads unwritten memory)
//   3. streams its 16x1024 weight tile (16 independent dwordx4 per thread),
//      MACs into a float4 partial, stores to Pcur;
//   4. grid barrier.
// ---------------------------------------------------------------------------
__global__ __launch_bounds__(NTHREADS, 2) void net_kernel(
    const float* __restrict__ x,
    const int*   __restrict__ node_inds,
    const float* __restrict__ Ws,
    const float* __restrict__ bs,
    float*       __restrict__ out,
    float*       __restrict__ outputs,
    float*       __restrict__ P0,
    float*       __restrict__ P1,
    int*         __restrict__ cnt)
{
    const int b    = blockIdx.x;
    const int t    = threadIdx.x;
    const int wv   = t >> 6;          // wave 0..3
    const int lane = t & 63;
    const int jhalf = b & 1;
    const int kc    = b >> 1;
    const int jbase = jhalf * JTILE + t * 4;
    const int col   = b * 4 + wv;     // this wave's owned state column

    __shared__ float gsh[RK];

    for (int i = 0; i < L_LAYERS; ++i) {
        const float* Pprev = (i & 1) ? P0 : P1;   // buffer written at layer i-1
        float*       Pcur  = (i & 1) ? P1 : P0;

        // ---- 1. finalize owned column of slot i
        if (i == 0) {
            if (lane == 0) outputs[col] = x[col];
        } else {
            float s = col_reduce(Pprev, col);
            float y = tanhf(s + bs[(i - 1) * UNITS + col]);
            if (lane == 0) outputs[(size_t)i * UNITS + col] = y;
        }

        // ---- 2. gather activations (4 wave-uniform indices per wave)
        #pragma unroll
        for (int j = 0; j < 4; ++j) {
            int q   = wv * 4 + j;
            int idx = node_inds[i * FANIN + kc * RK + q];
            float g;
            if (i == 0) {
                g = (idx < N_INPUTS) ? x[idx] : 0.f;
            } else if (idx < i * UNITS) {
                g = outputs[idx];
            } else if (idx < (i + 1) * UNITS) {
                int c = idx - i * UNITS;
                float s = col_reduce(Pprev, c);
                g = tanhf(s + bs[(i - 1) * UNITS + c]);
            } else {
                g = 0.f;
            }
            if (lane == 0) gsh[q] = g;
        }
        __syncthreads();

        // ---- 3. stream weight tile and MAC (16 independent loads in flight)
        const float4* W4 = (const float4*)(
            Ws + ((size_t)i * FANIN + (size_t)kc * RK) * UNITS + jbase);
        float4 a; a.x = 0.f; a.y = 0.f; a.z = 0.f; a.w = 0.f;
        #pragma unroll
        for (int k = 0; k < RK; ++k) {
            float  g = gsh[k];
            float4 w = W4[(size_t)k * (UNITS / 4)];   // row stride 2048 floats
            a.x += g * w.x; a.y += g * w.y; a.z += g * w.z; a.w += g * w.w;
        }
        *(float4*)(Pcur + (size_t)kc * UNITS + jbase) = a;

        // ---- 4. barrier
        grid_barrier(&cnt[i]);
    }

    // ---- epilogue: layer 7 wrote P1 (i=7 odd -> Pcur=P1)
    {
        float s = col_reduce(P1, col);
        float y = tanhf(s + bs[(L_LAYERS - 1) * UNITS + col]);
        if (lane == 0) out[col] = y;
    }
}

// ---------------------------------------------------------------------------
extern "C" void kernel_launch(void* const* d_in, const int* in_sizes, int n_in,
                              void* d_out, int out_size, void* d_ws, size_t ws_size,
                              hipStream_t stream) {
    const float* x         = (const float*)d_in[0];
    const int*   node_inds = (const int*)  d_in[1];
    const float* Ws        = (const float*)d_in[2];
    const float* bs        = (const float*)d_in[3];
    float*       out       = (float*)d_out;
    float*       ws        = (float*)d_ws;

    float* outputs = ws;                        // TOTAL floats
    float* P0      = outputs + TOTAL;           // KC*UNITS floats (2 MiB)
    float* P1      = P0 + (size_t)KC * UNITS;   // KC*UNITS floats (2 MiB)
    int*   cnt     = (int*)(P1 + (size_t)KC * UNITS);  // L_LAYERS ints

    init_kernel<<<1, 64, 0, stream>>>(cnt);
    net_kernel<<<NBLOCKS, NTHREADS, 0, stream>>>(
        x, node_inds, Ws, bs, out, outputs, P0, P1, cnt);
}

// Round 7
// 631.696 us; speedup vs baseline: 1.9017x; 1.3537x over previous
//
#include <hip/hip_runtime.h>
#include <cmath>

// Problem constants (from reference)
#define N_INPUTS 2048
#define UNITS    2048
#define L_LAYERS 8
#define FANIN    4096
#define TOTAL    18432           // N_INPUTS + L*UNITS

// Decomposition
#define NTHREADS 256
#define RK       16              // rows (k) per block per layer
#define KC       (FANIN / RK)    // 256 partial rows
#define JTILE    1024            // columns per block (256 thr * 4)
#define NBLOCKS  (2 * KC)        // 512 blocks: (j-half, k-chunk) — 2/CU, co-resident

// Barrier counters: module globals, zero-initialized at load, NEVER reset.
// Monotone epoch scheme: each counter rises by exactly NBLOCKS per call, so
// a block arriving with old value v waits for ((v & ~(NBLOCKS-1)) + NBLOCKS).
// Identical work every call => graph-capture safe. 64 B apart (no false sharing).
__device__ int g_cnt[L_LAYERS * 16];

// Agent-coherent scalar accesses: compile to sc-flagged global ops that
// write-through / read-past the non-coherent L1 / per-XCD L2 — NO cache-wide
// fence needed (the R5/R6 killer: __threadfence = full L2 wb/inv per block).
__device__ __forceinline__ void agent_store(float* p, float v) {
    __hip_atomic_store(p, v, __ATOMIC_RELAXED, __HIP_MEMORY_SCOPE_AGENT);
}
__device__ __forceinline__ float agent_load(const float* p) {
    return __hip_atomic_load(p, __ATOMIC_RELAXED, __HIP_MEMORY_SCOPE_AGENT);
}

// Wave-parallel reduction of one partials column (KC=256 rows), agent loads.
// All 64 lanes of the calling wave must participate. Returns sum in all lanes.
__device__ __forceinline__ float col_reduce(const float* __restrict__ P, int col)
{
    int lane = threadIdx.x & 63;
    float s = 0.f;
    #pragma unroll
    for (int m = 0; m < KC / 64; ++m)
        s += agent_load(P + (size_t)(lane + m * 64) * UNITS + col);
    #pragma unroll
    for (int off = 32; off; off >>= 1)
        s += __shfl_down(s, off, 64);
    return __shfl(s, 0, 64);
}

// Fence-free grid barrier. The compiler's own s_waitcnt vmcnt(0) before
// s_barrier (__syncthreads) drains every wave's agent-scope stores; arrival
// and polling are relaxed agent atomics (no cache maintenance whatsoever).
__device__ __forceinline__ void grid_barrier(int* cnt)
{
    __syncthreads();
    if (threadIdx.x == 0) {
        asm volatile("s_waitcnt vmcnt(0)" ::: "memory");  // belt & braces
        int old = __hip_atomic_fetch_add(cnt, 1, __ATOMIC_RELAXED,
                                         __HIP_MEMORY_SCOPE_AGENT);
        int target = (old & ~(NBLOCKS - 1)) + NBLOCKS;
        while (__hip_atomic_load(cnt, __ATOMIC_RELAXED,
                                 __HIP_MEMORY_SCOPE_AGENT) - target < 0)
            __builtin_amdgcn_s_sleep(16);
    }
    __syncthreads();
    asm volatile("" ::: "memory");   // no register-caching across the barrier
}

// ---------------------------------------------------------------------------
// Persistent fused kernel (single dispatch). Per layer i each block:
//   1. finalizes its 4 owned columns of state slot i from Pprev
//      (slot 0 = copy of x)                      [agent stores]
//   2. computes its 16 gather activations:
//        idx <  i*2048  -> outputs[idx]          [agent load, >=1 barrier old]
//        idx in slot i  -> recompute from Pprev  [agent loads]
//        idx beyond     -> 0
//   3. streams its 16x1024 weight tile with NORMAL cached loads (L2-friendly),
//      MACs, stores float4 partial as 4 agent stores to Pcur;
//   4. fence-free grid barrier.
// ---------------------------------------------------------------------------
__global__ __launch_bounds__(NTHREADS, 2) void net_kernel(
    const float* __restrict__ x,
    const int*   __restrict__ node_inds,
    const float* __restrict__ Ws,
    const float* __restrict__ bs,
    float*       __restrict__ out,
    float*       __restrict__ outputs,
    float*       __restrict__ P0,
    float*       __restrict__ P1)
{
    const int b    = blockIdx.x;
    const int t    = threadIdx.x;
    const int wv   = t >> 6;          // wave 0..3
    const int lane = t & 63;
    const int jhalf = b & 1;
    const int kc    = b >> 1;
    const int jbase = jhalf * JTILE + t * 4;
    const int col   = b * 4 + wv;     // this wave's owned state column

    __shared__ float gsh[RK];

    for (int i = 0; i < L_LAYERS; ++i) {
        const float* Pprev = (i & 1) ? P0 : P1;   // buffer written at layer i-1
        float*       Pcur  = (i & 1) ? P1 : P0;

        // ---- 1. finalize owned column of slot i
        if (i == 0) {
            if (lane == 0) agent_store(&outputs[col], x[col]);
        } else {
            float s = col_reduce(Pprev, col);
            float y = tanhf(s + bs[(i - 1) * UNITS + col]);
            if (lane == 0) agent_store(&outputs[(size_t)i * UNITS + col], y);
        }

        // ---- 2. gather activations (4 wave-uniform indices per wave)
        #pragma unroll
        for (int j = 0; j < 4; ++j) {
            int q   = wv * 4 + j;
            int idx = node_inds[i * FANIN + kc * RK + q];
            float g;
            if (i == 0) {
                g = (idx < N_INPUTS) ? x[idx] : 0.f;
            } else if (idx < i * UNITS) {
                g = agent_load(&outputs[idx]);
            } else if (idx < (i + 1) * UNITS) {
                int c = idx - i * UNITS;
                float s = col_reduce(Pprev, c);
                g = tanhf(s + bs[(i - 1) * UNITS + c]);
            } else {
                g = 0.f;
            }
            if (lane == 0) gsh[q] = g;
        }
        __syncthreads();

        // ---- 3. stream weight tile (cached loads) and MAC
        const float4* W4 = (const float4*)(
            Ws + ((size_t)i * FANIN + (size_t)kc * RK) * UNITS + jbase);
        float4 a; a.x = 0.f; a.y = 0.f; a.z = 0.f; a.w = 0.f;
        #pragma unroll
        for (int k = 0; k < RK; ++k) {
            float  g = gsh[k];
            float4 w = W4[(size_t)k * (UNITS / 4)];   // row stride 2048 floats
            a.x += g * w.x; a.y += g * w.y; a.z += g * w.z; a.w += g * w.w;
        }
        float* pc = Pcur + (size_t)kc * UNITS + jbase;
        agent_store(pc + 0, a.x);
        agent_store(pc + 1, a.y);
        agent_store(pc + 2, a.z);
        agent_store(pc + 3, a.w);

        // ---- 4. barrier
        grid_barrier(&g_cnt[i * 16]);
    }

    // ---- epilogue: layer 7 wrote P1 (i=7 odd -> Pcur=P1)
    {
        float s = col_reduce(P1, col);
        float y = tanhf(s + bs[(L_LAYERS - 1) * UNITS + col]);
        if (lane == 0) out[col] = y;
    }
}

// ---------------------------------------------------------------------------
extern "C" void kernel_launch(void* const* d_in, const int* in_sizes, int n_in,
                              void* d_out, int out_size, void* d_ws, size_t ws_size,
                              hipStream_t stream) {
    const float* x         = (const float*)d_in[0];
    const int*   node_inds = (const int*)  d_in[1];
    const float* Ws        = (const float*)d_in[2];
    const float* bs        = (const float*)d_in[3];
    float*       out       = (float*)d_out;
    float*       ws        = (float*)d_ws;

    float* outputs = ws;                        // TOTAL floats
    float* P0      = outputs + TOTAL;           // KC*UNITS floats (2 MiB)
    float* P1      = P0 + (size_t)KC * UNITS;   // KC*UNITS floats (2 MiB)

    net_kernel<<<NBLOCKS, NTHREADS, 0, stream>>>(
        x, node_inds, Ws, bs, out, outputs, P0, P1);
}